// Round 7
// baseline (257.277 us; speedup 1.0000x reference)
//
#include <hip/hip_runtime.h>

typedef __bf16 bf16;
typedef __bf16 bfx8 __attribute__((ext_vector_type(8)));
typedef __bf16 bfx4 __attribute__((ext_vector_type(4)));
typedef float f32x4 __attribute__((ext_vector_type(4)));

#define MFMA_BF16 __builtin_amdgcn_mfma_f32_16x16x32_bf16

static constexpr int Bq = 4, Sq = 2048, Dq = 1024, Hq = 16, HDq = 64;
static constexpr int Mq = Bq * Sq;          // 8192
static constexpr int D3 = 3 * Dq;           // 3072
static constexpr int NQK = 2 * Dq;          // 2048: Q,K row stride in qkv2
static constexpr float L2E = 1.4426950408889634f;
static constexpr float QSC = 0.125f * L2E;  // softmax scale folded into Q

typedef const __attribute__((address_space(1))) void* gas1;
typedef __attribute__((address_space(3))) void* las3;

__device__ __forceinline__ void gload_lds16(const bf16* g, bf16* l) {
    __builtin_amdgcn_global_load_lds((gas1)g, (las3)l, 16, 0, 0);
}

__device__ __forceinline__ float fast_exp2(float x) {
    return __builtin_amdgcn_exp2f(x);
}

// ---------------- fused prep: cast x (8192 blocks) + transpose w_qkv (3072) +
// ---------------- transpose w_out (1024) in ONE launch
__global__ __launch_bounds__(256) void prep(const float* __restrict__ x,
                                            const float* __restrict__ w_qkv,
                                            const float* __restrict__ w_out,
                                            bf16* __restrict__ x_bf,
                                            bf16* __restrict__ wqkvT,
                                            bf16* __restrict__ woutT) {
    __shared__ float tile[32][33];
    int bid = blockIdx.x, tid = threadIdx.x;
    if (bid < 8192) {                       // cast x: fp32 -> bf16
        int i = (bid * 256 + tid) * 4;
        float4 v = *(const float4*)(x + i);
        bfx4 r;
        r[0] = (bf16)v.x; r[1] = (bf16)v.y; r[2] = (bf16)v.z; r[3] = (bf16)v.w;
        *(bfx4*)(x_bf + i) = r;
        return;
    }
    const float* in; bf16* out; int R, C, blk;
    if (bid < 8192 + 3072) { blk = bid - 8192;  in = w_qkv; out = wqkvT; R = Dq; C = D3; }
    else                   { blk = bid - 11264; in = w_out; out = woutT; R = Dq; C = Dq; }
    int tx = tid & 31, ty = tid >> 5;       // 32 x 8
    int nbx = C / 32;
    int c0 = (blk % nbx) * 32, r0 = (blk / nbx) * 32;
    for (int j = 0; j < 32; j += 8)
        tile[ty + j][tx] = in[(size_t)(r0 + ty + j) * C + c0 + tx];
    __syncthreads();
    for (int j = 0; j < 32; j += 8)
        out[(size_t)(c0 + ty + j) * R + r0 + tx] = (bf16)tile[tx][ty + j];
}

// swizzled LDS byte offset for the V-transpose epilogue: [128 d][128 s] bf16 tile,
// 16B pair index XORed with (d&15) -> every write/read pattern <=2-way (free, m136)
__device__ __forceinline__ int ldsb(int d, int s) {
    return d * 256 + ((((s >> 3) ^ (d & 15)) << 4) | ((s & 7) * 2));
}

// ---------------- GEMM: C[M,N] = A[M,K] * Bt[N,K]^T, bf16 in, fp32 acc ----------------
// m97-structure 128^2 tile, natural block order (XCD swizzle measured -17.5us here).
// VSPLIT (QKV GEMM): n0<2048 -> Q,K into Cqk (stride 2048, Q pre-scaled); n0>=2048 ->
//   pure V tiles: epilogue transposes 128x128 through the free 32KB LDS and stores
//   COALESCED 16B runs along s into Vt[b][d][s'], key-permuted per 64-group to match
//   the attention kernel's in-register P layout (key = 16*tp + 4*quad + r).
template <bool OUT_F32, bool QSCALE, bool VSPLIT>
__global__ __launch_bounds__(256) void gemm_bt(const bf16* __restrict__ A,
                                               const bf16* __restrict__ Bt,
                                               void* __restrict__ Cout,
                                               bf16* __restrict__ Vout,
                                               int M, int N, int K) {
    __shared__ bf16 smem[2 * 8192];         // As | Bs; reused as 32KB transpose buffer
    bf16* As = smem;
    bf16* Bs = smem + 8192;
    int m0 = blockIdx.y * 128;
    int n0 = blockIdx.x * 128;
    int tid = threadIdx.x;
    int lane = tid & 63, wave = tid >> 6;
    int quad = lane >> 4, l16 = lane & 15;
    int wr = wave >> 1, wc = wave & 1;
    int sw = l16 & 7;

    f32x4 acc[4][4] = {};

    for (int k0 = 0; k0 < K; k0 += 64) {
        __syncthreads();
        #pragma unroll
        for (int i = 0; i < 4; i++) {
            int c = i * 256 + tid;          // LDS dest = wave-uniform + lane*16B
            int row = c >> 3;
            int ch = (c & 7) ^ (row & 7);   // swizzled source chunk
            gload_lds16(A + (size_t)(m0 + row) * K + k0 + ch * 8, As + c * 8);
            gload_lds16(Bt + (size_t)(n0 + row) * K + k0 + ch * 8, Bs + c * 8);
        }
        __syncthreads();
        #pragma unroll
        for (int s = 0; s < 2; s++) {
            bfx8 af[4], bfr[4];
            #pragma unroll
            for (int i = 0; i < 4; i++)
                af[i] = *(const bfx8*)(As + (wr * 64 + i * 16 + l16) * 64 +
                                       ((s * 4 + quad) ^ sw) * 8);
            #pragma unroll
            for (int j = 0; j < 4; j++)
                bfr[j] = *(const bfx8*)(Bs + (wc * 64 + j * 16 + l16) * 64 +
                                        ((s * 4 + quad) ^ sw) * 8);
            #pragma unroll
            for (int i = 0; i < 4; i++)
                #pragma unroll
                for (int j = 0; j < 4; j++)
                    acc[i][j] = MFMA_BF16(af[i], bfr[j], acc[i][j], 0, 0, 0);
        }
    }

    if (VSPLIT && n0 >= NQK) {
        // ---- V tile: acc -> LDS (swizzled [d][s]) -> coalesced key-permuted store
        __syncthreads();                    // all waves done reading As/Bs
        #pragma unroll
        for (int i = 0; i < 4; i++)
            #pragma unroll
            for (int j = 0; j < 4; j++) {
                int d = wc * 64 + j * 16 + l16;
                int s0 = wr * 64 + i * 16 + quad * 4;
                bfx4 pv;
                #pragma unroll
                for (int r = 0; r < 4; r++) pv[r] = (bf16)acc[i][j][r];
                *(bfx4*)((char*)smem + ldsb(d, s0)) = pv;
            }
        __syncthreads();
        int b = m0 >> 11, st = m0 & (Sq - 1), d0 = n0 - NQK;
        int g = (lane >> 3) & 1, t8 = lane & 7;
        int ss = g * 64 + (t8 >> 2) * 32 + (t8 & 3) * 4;
        #pragma unroll
        for (int rep = 0; rep < 8; rep++) {
            int d = wave * 4 + (lane >> 4) + rep * 16;
            bfx4 lo = *(const bfx4*)((char*)smem + ldsb(d, ss));
            bfx4 hi = *(const bfx4*)((char*)smem + ldsb(d, ss + 16));
            bfx8 o8;
            #pragma unroll
            for (int r = 0; r < 4; r++) { o8[r] = lo[r]; o8[4 + r] = hi[r]; }
            *(bfx8*)(Vout + ((size_t)b * Dq + d0 + d) * Sq + st + g * 64 + t8 * 8) = o8;
        }
        return;
    }

    #pragma unroll
    for (int i = 0; i < 4; i++)
        #pragma unroll
        for (int j = 0; j < 4; j++) {
            int col = n0 + wc * 64 + j * 16 + l16;
            int cstride = VSPLIT ? NQK : N;
            float scale = (QSCALE && col < Dq) ? QSC : 1.0f;
            #pragma unroll
            for (int r = 0; r < 4; r++) {
                int row = m0 + wr * 64 + i * 16 + quad * 4 + r;
                if (OUT_F32)
                    ((float*)Cout)[(size_t)row * cstride + col] = acc[i][j][r];
                else
                    ((bf16*)Cout)[(size_t)row * cstride + col] = (bf16)(acc[i][j][r] * scale);
            }
        }
}

// ---------------- Flash attention: softmax-pipelined, 40KB LDS (4 blocks/CU) ------
// 1024 blocks; 4 waves; wave owns 32 q rows.  bid%8 == head%8 (XCD K/V L2 reuse).
// In-register P (key-permuted Vt; R3-verified, conflicts 0).  NEW: cross-chunk
// softmax pipeline (T15 regime): per iteration, QK(i) and PV(i-1) form ONE MFMA
// burst (36 independent MFMAs) and exp2(i) runs after -- its results are consumed
// only after the next barrier, so the softmax VALU work is off the critical path
// (s_barrier waits memory counters, not VALU).  V is triple-buffered: prefetch(i+1)
// targets the buffer of chunk i-2, last read by PV(i-2) during iter i-1, fenced by
// the barrier at iter i.  Ks[2]+Vs[3] = 40KB = exactly 4 blocks/CU.
__global__ __launch_bounds__(256, 4) void attn_kernel(const bf16* __restrict__ qkv,
                                                      const bf16* __restrict__ Vt,
                                                      bf16* __restrict__ out) {
    __shared__ bf16 Ks[2][64 * 64];
    __shared__ bf16 Vs[3][64 * 64];

    int bid = blockIdx.x;
    int qc = (bid >> 3) & 15;                     // q chunk of 128
    int head = ((bid >> 7) << 3) | (bid & 7);     // 0..63; head%8 == bid%8
    int h = head & 15, b = head >> 4;
    int tid = threadIdx.x;
    int lane = tid & 63, wave = tid >> 6;
    int quad = lane >> 4, l16 = lane & 15;
    int sw = l16 & 7;

    size_t base = (size_t)b * Sq * NQK;
    const bf16* Kbase = qkv + base + Dq + h * HDq;
    const bf16* Vbase = Vt + ((size_t)b * Dq + h * HDq) * Sq;
    int q0 = qc * 128 + wave * 32;

    bfx8 qf[2][2];
    #pragma unroll
    for (int qt = 0; qt < 2; qt++)
        #pragma unroll
        for (int s = 0; s < 2; s++)
            qf[qt][s] = *(const bfx8*)(qkv + base + (size_t)(q0 + qt * 16 + l16) * NQK +
                                       h * HDq + s * 32 + quad * 8);

    bfx8 ones;
    #pragma unroll
    for (int j = 0; j < 8; j++) ones[j] = (bf16)1.0f;

    f32x4 oacc[2][4] = {};
    f32x4 lacc[2] = {};
    bfx8 pfp[2][2];                 // P of previous chunk: [hf][qt]

    int c0 = tid, c1 = tid + 256;
    int r0 = c0 >> 3, ch0 = (c0 & 7) ^ (r0 & 7);
    int r1 = c1 >> 3, ch1 = (c1 & 7) ^ (r1 & 7);

    // V buffer rotation: at top of iter i, vC = V(i), vP = V(i-1), vN = target for i+1
    bf16 *vP = Vs[2], *vC = Vs[0], *vN = Vs[1];

    // prologue: chunk 0 -> Ks[0], Vs[0]
    gload_lds16(Kbase + (size_t)r0 * NQK + ch0 * 8, Ks[0] + c0 * 8);
    gload_lds16(Vbase + (size_t)r0 * Sq + ch0 * 8, vC + c0 * 8);
    gload_lds16(Kbase + (size_t)r1 * NQK + ch1 * 8, Ks[0] + c1 * 8);
    gload_lds16(Vbase + (size_t)r1 * Sq + ch1 * 8, vC + c1 * 8);

    for (int i = 0; i < 32; i++) {
        __syncthreads();            // prefetch(i) landed; V(i-2) buffer reusable
        if (i + 1 < 32) {
            int k0 = (i + 1) * 64;
            bf16* kd = Ks[(i + 1) & 1];
            gload_lds16(Kbase + (size_t)(k0 + r0) * NQK + ch0 * 8, kd + c0 * 8);
            gload_lds16(Vbase + (size_t)r0 * Sq + k0 + ch0 * 8, vN + c0 * 8);
            gload_lds16(Kbase + (size_t)(k0 + r1) * NQK + ch1 * 8, kd + c1 * 8);
            gload_lds16(Vbase + (size_t)r1 * Sq + k0 + ch1 * 8, vN + c1 * 8);
        }
        const bf16* K_ = Ks[i & 1];

        // QK^T(i) half 0
        f32x4 sc[2][2][2];          // [hf][qt][tp] -- fully unrolled, stays in regs
        #pragma unroll
        for (int hf = 0; hf < 1; hf++) {
            bfx8 kf[2][2];
            #pragma unroll
            for (int tp = 0; tp < 2; tp++) {
                int krow = ((2 * hf + tp) * 16 + l16) * 64;
                kf[tp][0] = *(const bfx8*)(K_ + krow + (quad ^ sw) * 8);
                kf[tp][1] = *(const bfx8*)(K_ + krow + ((4 + quad) ^ sw) * 8);
            }
            #pragma unroll
            for (int qt = 0; qt < 2; qt++) {
                f32x4 s0 = {}, s1 = {};
                s0 = MFMA_BF16(kf[0][0], qf[qt][0], s0, 0, 0, 0);
                s0 = MFMA_BF16(kf[0][1], qf[qt][1], s0, 0, 0, 0);
                s1 = MFMA_BF16(kf[1][0], qf[qt][0], s1, 0, 0, 0);
                s1 = MFMA_BF16(kf[1][1], qf[qt][1], s1, 0, 0, 0);
                sc[hf][qt][0] = s0; sc[hf][qt][1] = s1;
            }
        }

        // PV(i-1): independent of QK(i) -> merges into one MFMA burst
        if (i > 0) {
            #pragma unroll
            for (int hf = 0; hf < 2; hf++) {
                lacc[0] = MFMA_BF16(pfp[hf][0], ones, lacc[0], 0, 0, 0);
                lacc[1] = MFMA_BF16(pfp[hf][1], ones, lacc[1], 0, 0, 0);
                #pragma unroll
                for (int nt = 0; nt < 4; nt++) {
                    bfx8 vf = *(const bfx8*)(vP + (nt * 16 + l16) * 64 +
                                             ((hf * 4 + quad) ^ sw) * 8);
                    oacc[0][nt] = MFMA_BF16(pfp[hf][0], vf, oacc[0][nt], 0, 0, 0);
                    oacc[1][nt] = MFMA_BF16(pfp[hf][1], vf, oacc[1][nt], 0, 0, 0);
                }
            }
        }

        // QK^T(i) half 1
        #pragma unroll
        for (int hf = 1; hf < 2; hf++) {
            bfx8 kf[2][2];
            #pragma unroll
            for (int tp = 0; tp < 2; tp++) {
                int krow = ((2 * hf + tp) * 16 + l16) * 64;
                kf[tp][0] = *(const bfx8*)(K_ + krow + (quad ^ sw) * 8);
                kf[tp][1] = *(const bfx8*)(K_ + krow + ((4 + quad) ^ sw) * 8);
            }
            #pragma unroll
            for (int qt = 0; qt < 2; qt++) {
                f32x4 s0 = {}, s1 = {};
                s0 = MFMA_BF16(kf[0][0], qf[qt][0], s0, 0, 0, 0);
                s0 = MFMA_BF16(kf[0][1], qf[qt][1], s0, 0, 0, 0);
                s1 = MFMA_BF16(kf[1][0], qf[qt][0], s1, 0, 0, 0);
                s1 = MFMA_BF16(kf[1][1], qf[qt][1], s1, 0, 0, 0);
                sc[hf][qt][0] = s0; sc[hf][qt][1] = s1;
            }
        }

        // exp2(i) -> P(i): consumed only after the next barrier (off critical path)
        #pragma unroll
        for (int hf = 0; hf < 2; hf++)
            #pragma unroll
            for (int qt = 0; qt < 2; qt++) {
                bfx8 p;
                #pragma unroll
                for (int r = 0; r < 4; r++) {
                    p[r]     = (bf16)fast_exp2(sc[hf][qt][0][r]);   // key 4*quad + r
                    p[4 + r] = (bf16)fast_exp2(sc[hf][qt][1][r]);   // key 16+4*quad+r
                }
                pfp[hf][qt] = p;
            }

        // rotate V buffers: (vP, vC, vN) <- (vC, vN, vP)
        bf16* t = vP; vP = vC; vC = vN; vN = t;
    }

    // drain: PV for chunk 31 (in vP after final rotation)
    #pragma unroll
    for (int hf = 0; hf < 2; hf++) {
        lacc[0] = MFMA_BF16(pfp[hf][0], ones, lacc[0], 0, 0, 0);
        lacc[1] = MFMA_BF16(pfp[hf][1], ones, lacc[1], 0, 0, 0);
        #pragma unroll
        for (int nt = 0; nt < 4; nt++) {
            bfx8 vf = *(const bfx8*)(vP + (nt * 16 + l16) * 64 +
                                     ((hf * 4 + quad) ^ sw) * 8);
            oacc[0][nt] = MFMA_BF16(pfp[hf][0], vf, oacc[0][nt], 0, 0, 0);
            oacc[1][nt] = MFMA_BF16(pfp[hf][1], vf, oacc[1][nt], 0, 0, 0);
        }
    }

    #pragma unroll
    for (int qt = 0; qt < 2; qt++)
        #pragma unroll
        for (int r = 0; r < 4; r++) {
            int row = q0 + qt * 16 + quad * 4 + r;
            float inv = 1.0f / lacc[qt][r];
            #pragma unroll
            for (int nt = 0; nt < 4; nt++)
                out[((size_t)b * Sq + row) * Dq + h * HDq + nt * 16 + l16] =
                    (bf16)(oacc[qt][nt][r] * inv);
        }
}

extern "C" void kernel_launch(void* const* d_in, const int* in_sizes, int n_in,
                              void* d_out, int out_size, void* d_ws, size_t ws_size,
                              hipStream_t stream) {
    const float* x     = (const float*)d_in[0];
    const float* w_qkv = (const float*)d_in[1];
    const float* w_out = (const float*)d_in[2];
    float* out = (float*)d_out;

    char* ws = (char*)d_ws;
    bf16* x_bf   = (bf16*)ws;                                   // 16 MB (dead after gemm1)
    bf16* wqkvT  = (bf16*)(ws + 16777216);                      //  6 MB
    bf16* woutT  = (bf16*)(ws + 16777216 + 6291456);            //  2 MB
    bf16* qkv2   = (bf16*)(ws + 25165824);                      // 32 MB: Q,K stride 2048
    bf16* Vt     = (bf16*)(ws + 25165824 + 33554432);           // 16 MB: V^T key-permuted
    bf16* attn   = x_bf;   // x_bf dead after gemm1; reuse for attention output

    // 1. prep: cast x + transpose both weights (single launch)
    prep<<<8192 + 3072 + 1024, 256, 0, stream>>>(x, w_qkv, w_out, x_bf, wqkvT, woutT);

    // 2. qkv = x @ w_qkv: Q,K -> qkv2 (Q pre-scaled); V -> Vt via coalesced LDS epilogue
    gemm_bt<false, true, true><<<dim3(D3 / 128, Mq / 128), 256, 0, stream>>>(
        x_bf, wqkvT, qkv2, Vt, Mq, D3, Dq);

    // 3. attention (1024 blocks, XCD-affine, 40KB LDS, softmax-pipelined)
    attn_kernel<<<1024, 256, 0, stream>>>(qkv2, Vt, attn);

    // 4. out = attn @ w_out  [8192 x 1024], fp32 out
    gemm_bt<true, false, false><<<dim3(Dq / 128, Mq / 128), 256, 0, stream>>>(
        attn, woutT, out, nullptr, Mq, Dq, Dq);
}

// Round 8
// 244.274 us; speedup vs baseline: 1.0532x; 1.0532x over previous
//
#include <hip/hip_runtime.h>

typedef __bf16 bf16;
typedef __bf16 bfx8 __attribute__((ext_vector_type(8)));
typedef __bf16 bfx4 __attribute__((ext_vector_type(4)));
typedef float f32x4 __attribute__((ext_vector_type(4)));

#define MFMA_BF16 __builtin_amdgcn_mfma_f32_16x16x32_bf16

static constexpr int Bq = 4, Sq = 2048, Dq = 1024, Hq = 16, HDq = 64;
static constexpr int Mq = Bq * Sq;          // 8192
static constexpr int D3 = 3 * Dq;           // 3072
static constexpr int NQK = 2 * Dq;          // 2048: Q,K row stride in qkv2
static constexpr float L2E = 1.4426950408889634f;
static constexpr float QSC = 0.125f * L2E;  // softmax scale folded into Q

typedef const __attribute__((address_space(1))) void* gas1;
typedef __attribute__((address_space(3))) void* las3;

__device__ __forceinline__ void gload_lds16(const bf16* g, bf16* l) {
    __builtin_amdgcn_global_load_lds((gas1)g, (las3)l, 16, 0, 0);
}

__device__ __forceinline__ float fast_exp2(float x) {
    return __builtin_amdgcn_exp2f(x);
}

// ---------------- fused prep: cast x (8192 blocks) + transpose w_qkv (3072) +
// ---------------- transpose w_out (1024) in ONE launch
__global__ __launch_bounds__(256) void prep(const float* __restrict__ x,
                                            const float* __restrict__ w_qkv,
                                            const float* __restrict__ w_out,
                                            bf16* __restrict__ x_bf,
                                            bf16* __restrict__ wqkvT,
                                            bf16* __restrict__ woutT) {
    __shared__ float tile[32][33];
    int bid = blockIdx.x, tid = threadIdx.x;
    if (bid < 8192) {                       // cast x: fp32 -> bf16
        int i = (bid * 256 + tid) * 4;
        float4 v = *(const float4*)(x + i);
        bfx4 r;
        r[0] = (bf16)v.x; r[1] = (bf16)v.y; r[2] = (bf16)v.z; r[3] = (bf16)v.w;
        *(bfx4*)(x_bf + i) = r;
        return;
    }
    const float* in; bf16* out; int R, C, blk;
    if (bid < 8192 + 3072) { blk = bid - 8192;  in = w_qkv; out = wqkvT; R = Dq; C = D3; }
    else                   { blk = bid - 11264; in = w_out; out = woutT; R = Dq; C = Dq; }
    int tx = tid & 31, ty = tid >> 5;       // 32 x 8
    int nbx = C / 32;
    int c0 = (blk % nbx) * 32, r0 = (blk / nbx) * 32;
    for (int j = 0; j < 32; j += 8)
        tile[ty + j][tx] = in[(size_t)(r0 + ty + j) * C + c0 + tx];
    __syncthreads();
    for (int j = 0; j < 32; j += 8)
        out[(size_t)(c0 + ty + j) * R + r0 + tx] = (bf16)tile[tx][ty + j];
}

// swizzled LDS byte offset for the V-transpose epilogue: [128 d][128 s] bf16 tile,
// 16B pair index XORed with (d&15) -> every write/read pattern <=2-way (free, m136)
__device__ __forceinline__ int ldsb(int d, int s) {
    return d * 256 + ((((s >> 3) ^ (d & 15)) << 4) | ((s & 7) * 2));
}

// ---------------- GEMM: C[M,N] = A[M,K] * Bt[N,K]^T, bf16 in, fp32 acc ----------------
// m97-structure 128^2 tile, natural block order (XCD swizzle measured -17.5us here).
// VSPLIT (QKV GEMM): n0<2048 -> Q,K into Cqk (stride 2048, Q pre-scaled); n0>=2048 ->
//   pure V tiles: epilogue transposes 128x128 through the free 32KB LDS and stores
//   COALESCED 16B runs along s into Vt[b][d][s'], key-permuted per 64-group to match
//   the attention kernel's in-register P layout (key = 16*tp + 4*quad + r).
template <bool OUT_F32, bool QSCALE, bool VSPLIT>
__global__ __launch_bounds__(256) void gemm_bt(const bf16* __restrict__ A,
                                               const bf16* __restrict__ Bt,
                                               void* __restrict__ Cout,
                                               bf16* __restrict__ Vout,
                                               int M, int N, int K) {
    __shared__ bf16 smem[2 * 8192];         // As | Bs; reused as 32KB transpose buffer
    bf16* As = smem;
    bf16* Bs = smem + 8192;
    int m0 = blockIdx.y * 128;
    int n0 = blockIdx.x * 128;
    int tid = threadIdx.x;
    int lane = tid & 63, wave = tid >> 6;
    int quad = lane >> 4, l16 = lane & 15;
    int wr = wave >> 1, wc = wave & 1;
    int sw = l16 & 7;

    f32x4 acc[4][4] = {};

    for (int k0 = 0; k0 < K; k0 += 64) {
        __syncthreads();
        #pragma unroll
        for (int i = 0; i < 4; i++) {
            int c = i * 256 + tid;          // LDS dest = wave-uniform + lane*16B
            int row = c >> 3;
            int ch = (c & 7) ^ (row & 7);   // swizzled source chunk
            gload_lds16(A + (size_t)(m0 + row) * K + k0 + ch * 8, As + c * 8);
            gload_lds16(Bt + (size_t)(n0 + row) * K + k0 + ch * 8, Bs + c * 8);
        }
        __syncthreads();
        #pragma unroll
        for (int s = 0; s < 2; s++) {
            bfx8 af[4], bfr[4];
            #pragma unroll
            for (int i = 0; i < 4; i++)
                af[i] = *(const bfx8*)(As + (wr * 64 + i * 16 + l16) * 64 +
                                       ((s * 4 + quad) ^ sw) * 8);
            #pragma unroll
            for (int j = 0; j < 4; j++)
                bfr[j] = *(const bfx8*)(Bs + (wc * 64 + j * 16 + l16) * 64 +
                                        ((s * 4 + quad) ^ sw) * 8);
            #pragma unroll
            for (int i = 0; i < 4; i++)
                #pragma unroll
                for (int j = 0; j < 4; j++)
                    acc[i][j] = MFMA_BF16(af[i], bfr[j], acc[i][j], 0, 0, 0);
        }
    }

    if (VSPLIT && n0 >= NQK) {
        // ---- V tile: acc -> LDS (swizzled [d][s]) -> coalesced key-permuted store
        __syncthreads();                    // all waves done reading As/Bs
        #pragma unroll
        for (int i = 0; i < 4; i++)
            #pragma unroll
            for (int j = 0; j < 4; j++) {
                int d = wc * 64 + j * 16 + l16;
                int s0 = wr * 64 + i * 16 + quad * 4;
                bfx4 pv;
                #pragma unroll
                for (int r = 0; r < 4; r++) pv[r] = (bf16)acc[i][j][r];
                *(bfx4*)((char*)smem + ldsb(d, s0)) = pv;
            }
        __syncthreads();
        int b = m0 >> 11, st = m0 & (Sq - 1), d0 = n0 - NQK;
        int g = (lane >> 3) & 1, t8 = lane & 7;
        int ss = g * 64 + (t8 >> 2) * 32 + (t8 & 3) * 4;
        #pragma unroll
        for (int rep = 0; rep < 8; rep++) {
            int d = wave * 4 + (lane >> 4) + rep * 16;
            bfx4 lo = *(const bfx4*)((char*)smem + ldsb(d, ss));
            bfx4 hi = *(const bfx4*)((char*)smem + ldsb(d, ss + 16));
            bfx8 o8;
            #pragma unroll
            for (int r = 0; r < 4; r++) { o8[r] = lo[r]; o8[4 + r] = hi[r]; }
            *(bfx8*)(Vout + ((size_t)b * Dq + d0 + d) * Sq + st + g * 64 + t8 * 8) = o8;
        }
        return;
    }

    #pragma unroll
    for (int i = 0; i < 4; i++)
        #pragma unroll
        for (int j = 0; j < 4; j++) {
            int col = n0 + wc * 64 + j * 16 + l16;
            int cstride = VSPLIT ? NQK : N;
            float scale = (QSCALE && col < Dq) ? QSC : 1.0f;
            #pragma unroll
            for (int r = 0; r < 4; r++) {
                int row = m0 + wr * 64 + i * 16 + quad * 4 + r;
                if (OUT_F32)
                    ((float*)Cout)[(size_t)row * cstride + col] = acc[i][j][r];
                else
                    ((bf16*)Cout)[(size_t)row * cstride + col] = (bf16)(acc[i][j][r] * scale);
            }
        }
}

// ---------------- Flash attention: counted-vmcnt pipeline, 40KB LDS (4 blocks/CU) --
// 1024 blocks; 4 waves; wave owns 32 q rows.  bid%8 == head%8 (XCD K/V L2 reuse).
// In-register P via key-permuted Vt (R3-verified; bank conflicts 0).  NEW (T4):
// raw s_barrier + counted s_waitcnt vmcnt(2) -- the per-iteration __syncthreads
// drain (vmcnt(0)) exposed load latency at every one of 32 barriers; now only K(i+1)
// stays in flight across each boundary and the loop never drains until the tail.
//   Ledger (2 loads per issue group, in-order vmcnt retirement): prologue issues
//   K0,V0,K1.  Iter i waits vmcnt(2) -> everything except K(i+1) retired, i.e.
//   K(i),V(i) landed; barrier (all waves' tiles in LDS; all waves done reading
//   chunk i-1); THEN issue V(i+1)->Vbuf[(i+1)&1] (held V(i-1), done pre-barrier)
//   and K(i+2)->Kbuf[(i+2)%3] (held K(i-1), done pre-barrier); compute chunk i.
//   K triple-buffered, V double-buffered: 5 x 8KB = 40KB -> 4 blocks/CU kept.
__global__ __launch_bounds__(256, 4) void attn_kernel(const bf16* __restrict__ qkv,
                                                      const bf16* __restrict__ Vt,
                                                      bf16* __restrict__ out) {
    __shared__ bf16 Ks[3][64 * 64];
    __shared__ bf16 Vs[2][64 * 64];

    int bid = blockIdx.x;
    int qc = (bid >> 3) & 15;                     // q chunk of 128
    int head = ((bid >> 7) << 3) | (bid & 7);     // 0..63; head%8 == bid%8
    int h = head & 15, b = head >> 4;
    int tid = threadIdx.x;
    int lane = tid & 63, wave = tid >> 6;
    int quad = lane >> 4, l16 = lane & 15;
    int sw = l16 & 7;

    size_t base = (size_t)b * Sq * NQK;
    const bf16* Kbase = qkv + base + Dq + h * HDq;
    const bf16* Vbase = Vt + ((size_t)b * Dq + h * HDq) * Sq;
    int q0 = qc * 128 + wave * 32;

    bfx8 qf[2][2];
    #pragma unroll
    for (int qt = 0; qt < 2; qt++)
        #pragma unroll
        for (int s = 0; s < 2; s++)
            qf[qt][s] = *(const bfx8*)(qkv + base + (size_t)(q0 + qt * 16 + l16) * NQK +
                                       h * HDq + s * 32 + quad * 8);

    bfx8 ones;
    #pragma unroll
    for (int j = 0; j < 8; j++) ones[j] = (bf16)1.0f;

    f32x4 oacc[2][4] = {};
    f32x4 lacc[2] = {};

    int c0 = tid, c1 = tid + 256;
    int r0 = c0 >> 3, ch0 = (c0 & 7) ^ (r0 & 7);
    int r1 = c1 >> 3, ch1 = (c1 & 7) ^ (r1 & 7);

    // K buffer rotation: kC = K(i), kN = K(i+1), kF = target for K(i+2)
    bf16 *kC = Ks[0], *kN = Ks[1], *kF = Ks[2];
    bf16 *vC = Vs[0], *vN = Vs[1];

    // prologue: K0, V0, K1   (6 loads/thread outstanding)
    gload_lds16(Kbase + (size_t)r0 * NQK + ch0 * 8, kC + c0 * 8);
    gload_lds16(Kbase + (size_t)r1 * NQK + ch1 * 8, kC + c1 * 8);
    gload_lds16(Vbase + (size_t)r0 * Sq + ch0 * 8, vC + c0 * 8);
    gload_lds16(Vbase + (size_t)r1 * Sq + ch1 * 8, vC + c1 * 8);
    gload_lds16(Kbase + (size_t)(64 + r0) * NQK + ch0 * 8, kN + c0 * 8);
    gload_lds16(Kbase + (size_t)(64 + r1) * NQK + ch1 * 8, kN + c1 * 8);

    #pragma unroll 1
    for (int i = 0; i < 32; i++) {
        if (i < 31) asm volatile("s_waitcnt vmcnt(2)" ::: "memory");
        else        asm volatile("s_waitcnt vmcnt(0)" ::: "memory");
        __builtin_amdgcn_s_barrier();
        if (i + 1 < 32) {           // V(i+1) -> buffer of V(i-1) (safe post-barrier)
            int k0 = (i + 1) * 64;
            gload_lds16(Vbase + (size_t)r0 * Sq + k0 + ch0 * 8, vN + c0 * 8);
            gload_lds16(Vbase + (size_t)r1 * Sq + k0 + ch1 * 8, vN + c1 * 8);
        }
        if (i + 2 < 32) {           // K(i+2) -> buffer of K(i-1) (safe post-barrier)
            int k0 = (i + 2) * 64;
            gload_lds16(Kbase + (size_t)(k0 + r0) * NQK + ch0 * 8, kF + c0 * 8);
            gload_lds16(Kbase + (size_t)(k0 + r1) * NQK + ch1 * 8, kF + c1 * 8);
        }
        const bf16* K_ = kC;
        const bf16* V_ = vC;

        #pragma unroll
        for (int hf = 0; hf < 2; hf++) {
            bfx8 kf[2][2];
            #pragma unroll
            for (int tp = 0; tp < 2; tp++) {
                int krow = ((2 * hf + tp) * 16 + l16) * 64;
                kf[tp][0] = *(const bfx8*)(K_ + krow + (quad ^ sw) * 8);
                kf[tp][1] = *(const bfx8*)(K_ + krow + ((4 + quad) ^ sw) * 8);
            }

            bfx8 pf[2];
            #pragma unroll
            for (int qt = 0; qt < 2; qt++) {
                f32x4 s0 = {}, s1 = {};
                s0 = MFMA_BF16(kf[0][0], qf[qt][0], s0, 0, 0, 0);
                s0 = MFMA_BF16(kf[0][1], qf[qt][1], s0, 0, 0, 0);
                s1 = MFMA_BF16(kf[1][0], qf[qt][0], s1, 0, 0, 0);
                s1 = MFMA_BF16(kf[1][1], qf[qt][1], s1, 0, 0, 0);
                bfx8 p;
                #pragma unroll
                for (int r = 0; r < 4; r++) {
                    p[r]     = (bf16)fast_exp2(s0[r]);   // key 4*quad + r
                    p[4 + r] = (bf16)fast_exp2(s1[r]);   // key 16 + 4*quad + r
                }
                pf[qt] = p;
                lacc[qt] = MFMA_BF16(pf[qt], ones, lacc[qt], 0, 0, 0);
            }

            #pragma unroll
            for (int nt = 0; nt < 4; nt++) {
                bfx8 vf = *(const bfx8*)(V_ + (nt * 16 + l16) * 64 +
                                         ((hf * 4 + quad) ^ sw) * 8);
                oacc[0][nt] = MFMA_BF16(pf[0], vf, oacc[0][nt], 0, 0, 0);
                oacc[1][nt] = MFMA_BF16(pf[1], vf, oacc[1][nt], 0, 0, 0);
            }
        }

        // rotate buffers
        bf16* kt = kC; kC = kN; kN = kF; kF = kt;
        bf16* vt = vC; vC = vN; vN = vt;
    }

    #pragma unroll
    for (int qt = 0; qt < 2; qt++)
        #pragma unroll
        for (int r = 0; r < 4; r++) {
            int row = q0 + qt * 16 + quad * 4 + r;
            float inv = 1.0f / lacc[qt][r];
            #pragma unroll
            for (int nt = 0; nt < 4; nt++)
                out[((size_t)b * Sq + row) * Dq + h * HDq + nt * 16 + l16] =
                    (bf16)(oacc[qt][nt][r] * inv);
        }
}

extern "C" void kernel_launch(void* const* d_in, const int* in_sizes, int n_in,
                              void* d_out, int out_size, void* d_ws, size_t ws_size,
                              hipStream_t stream) {
    const float* x     = (const float*)d_in[0];
    const float* w_qkv = (const float*)d_in[1];
    const float* w_out = (const float*)d_in[2];
    float* out = (float*)d_out;

    char* ws = (char*)d_ws;
    bf16* x_bf   = (bf16*)ws;                                   // 16 MB (dead after gemm1)
    bf16* wqkvT  = (bf16*)(ws + 16777216);                      //  6 MB
    bf16* woutT  = (bf16*)(ws + 16777216 + 6291456);            //  2 MB
    bf16* qkv2   = (bf16*)(ws + 25165824);                      // 32 MB: Q,K stride 2048
    bf16* Vt     = (bf16*)(ws + 25165824 + 33554432);           // 16 MB: V^T key-permuted
    bf16* attn   = x_bf;   // x_bf dead after gemm1; reuse for attention output

    // 1. prep: cast x + transpose both weights (single launch)
    prep<<<8192 + 3072 + 1024, 256, 0, stream>>>(x, w_qkv, w_out, x_bf, wqkvT, woutT);

    // 2. qkv = x @ w_qkv: Q,K -> qkv2 (Q pre-scaled); V -> Vt via coalesced LDS epilogue
    gemm_bt<false, true, true><<<dim3(D3 / 128, Mq / 128), 256, 0, stream>>>(
        x_bf, wqkvT, qkv2, Vt, Mq, D3, Dq);

    // 3. attention (1024 blocks, XCD-affine, 40KB LDS, counted-vmcnt pipeline)
    attn_kernel<<<1024, 256, 0, stream>>>(qkv2, Vt, attn);

    // 4. out = attn @ w_out  [8192 x 1024], fp32 out
    gemm_bt<true, false, false><<<dim3(Dq / 128, Mq / 128), 256, 0, stream>>>(
        attn, woutT, out, nullptr, Mq, Dq, Dq);
}

// Round 9
// 231.401 us; speedup vs baseline: 1.1118x; 1.0556x over previous
//
#include <hip/hip_runtime.h>

typedef __bf16 bf16;
typedef __bf16 bfx8 __attribute__((ext_vector_type(8)));
typedef __bf16 bfx4 __attribute__((ext_vector_type(4)));
typedef float f32x4 __attribute__((ext_vector_type(4)));

#define MFMA_BF16 __builtin_amdgcn_mfma_f32_16x16x32_bf16

static constexpr int Bq = 4, Sq = 2048, Dq = 1024, Hq = 16, HDq = 64;
static constexpr int Mq = Bq * Sq;          // 8192
static constexpr int D3 = 3 * Dq;           // 3072
static constexpr int NQK = 2 * Dq;          // 2048: Q,K row stride in qkv2
static constexpr float L2E = 1.4426950408889634f;
static constexpr float QSC = 0.125f * L2E;  // softmax scale folded into Q

typedef const __attribute__((address_space(1))) void* gas1;
typedef __attribute__((address_space(3))) void* las3;

__device__ __forceinline__ void gload_lds16(const bf16* g, bf16* l) {
    __builtin_amdgcn_global_load_lds((gas1)g, (las3)l, 16, 0, 0);
}

__device__ __forceinline__ float fast_exp2(float x) {
    return __builtin_amdgcn_exp2f(x);
}

// ---------------- fused prep: cast x (8192 blocks) + transpose w_qkv (3072) +
// ---------------- transpose w_out (1024) in ONE launch
__global__ __launch_bounds__(256) void prep(const float* __restrict__ x,
                                            const float* __restrict__ w_qkv,
                                            const float* __restrict__ w_out,
                                            bf16* __restrict__ x_bf,
                                            bf16* __restrict__ wqkvT,
                                            bf16* __restrict__ woutT) {
    __shared__ float tile[32][33];
    int bid = blockIdx.x, tid = threadIdx.x;
    if (bid < 8192) {                       // cast x: fp32 -> bf16
        int i = (bid * 256 + tid) * 4;
        float4 v = *(const float4*)(x + i);
        bfx4 r;
        r[0] = (bf16)v.x; r[1] = (bf16)v.y; r[2] = (bf16)v.z; r[3] = (bf16)v.w;
        *(bfx4*)(x_bf + i) = r;
        return;
    }
    const float* in; bf16* out; int R, C, blk;
    if (bid < 8192 + 3072) { blk = bid - 8192;  in = w_qkv; out = wqkvT; R = Dq; C = D3; }
    else                   { blk = bid - 11264; in = w_out; out = woutT; R = Dq; C = Dq; }
    int tx = tid & 31, ty = tid >> 5;       // 32 x 8
    int nbx = C / 32;
    int c0 = (blk % nbx) * 32, r0 = (blk / nbx) * 32;
    for (int j = 0; j < 32; j += 8)
        tile[ty + j][tx] = in[(size_t)(r0 + ty + j) * C + c0 + tx];
    __syncthreads();
    for (int j = 0; j < 32; j += 8)
        out[(size_t)(c0 + ty + j) * R + r0 + tx] = (bf16)tile[tx][ty + j];
}

// swizzled LDS byte offset for the V-transpose epilogue: [128 d][128 s] bf16 tile,
// 16B pair index XORed with (d&15) -> every write/read pattern <=2-way (free, m136)
__device__ __forceinline__ int ldsb(int d, int s) {
    return d * 256 + ((((s >> 3) ^ (d & 15)) << 4) | ((s & 7) * 2));
}

// stage one 128x64 K-step of A and B into an LDS buffer (8 x global_load_lds_dwordx4)
__device__ __forceinline__ void stage_tile(const bf16* A, const bf16* Bt,
                                           bf16* As, bf16* Bs,
                                           int m0, int n0, int K, int k0, int tid) {
    #pragma unroll
    for (int i = 0; i < 4; i++) {
        int c = i * 256 + tid;              // LDS dest = wave-uniform + lane*16B
        int row = c >> 3;
        int ch = (c & 7) ^ (row & 7);       // swizzled source chunk
        gload_lds16(A + (size_t)(m0 + row) * K + k0 + ch * 8, As + c * 8);
        gload_lds16(Bt + (size_t)(n0 + row) * K + k0 + ch * 8, Bs + c * 8);
    }
}

// ---------------- GEMM: C[M,N] = A[M,K] * Bt[N,K]^T, bf16 in, fp32 acc ----------------
// m97-structure 128^2 tile + T3 minimum 2-phase pipeline (catalog recipe):
//   STAGE(t+1) issued BEFORE compute(t) -> staging latency hides under ds_read+MFMA;
//   end-of-step vmcnt(0)+s_barrier completes stage(t+1) (needed next step anyway) and
//   fences buffer reuse.  Raw s_barrier (not __syncthreads) avoids the implicit full
//   drain that exposed HBM/L2 latency at every one of the 16 K-steps (gemm1 was
//   latency-bound: MfmaUtil 26, VALUBusy 35, HBM 20%).  LDS 64KB dbuf, 2 blocks/CU.
// VSPLIT (QKV GEMM): n0<2048 -> Q,K into Cqk (stride 2048, Q pre-scaled); n0>=2048 ->
//   pure V tiles: epilogue transposes 128x128 through LDS and stores COALESCED 16B
//   runs along s into Vt[b][d][s'], key-permuted per 64-group to match the attention
//   kernel's in-register P layout (key = 16*tp + 4*quad + r).
template <bool OUT_F32, bool QSCALE, bool VSPLIT>
__global__ __launch_bounds__(256) void gemm_bt(const bf16* __restrict__ A,
                                               const bf16* __restrict__ Bt,
                                               void* __restrict__ Cout,
                                               bf16* __restrict__ Vout,
                                               int M, int N, int K) {
    __shared__ bf16 smem[4 * 8192];         // 2 bufs x (As 16KB | Bs 16KB) = 64KB
    int m0 = blockIdx.y * 128;
    int n0 = blockIdx.x * 128;
    int tid = threadIdx.x;
    int lane = tid & 63, wave = tid >> 6;
    int quad = lane >> 4, l16 = lane & 15;
    int wr = wave >> 1, wc = wave & 1;
    int sw = l16 & 7;

    f32x4 acc[4][4] = {};

    stage_tile(A, Bt, smem, smem + 8192, m0, n0, K, 0, tid);
    asm volatile("s_waitcnt vmcnt(0)" ::: "memory");
    __builtin_amdgcn_s_barrier();

    int nt = K >> 6;
    #pragma unroll 1
    for (int t = 0; t < nt; t++) {
        int cur = t & 1;
        if (t + 1 < nt)                     // overlap: issue next stage before compute
            stage_tile(A, Bt, smem + (cur ^ 1) * 16384, smem + (cur ^ 1) * 16384 + 8192,
                       m0, n0, K, (t + 1) * 64, tid);
        const bf16* As = smem + cur * 16384;
        const bf16* Bs = As + 8192;
        #pragma unroll
        for (int s = 0; s < 2; s++) {
            bfx8 af[4], bfr[4];
            #pragma unroll
            for (int i = 0; i < 4; i++)
                af[i] = *(const bfx8*)(As + (wr * 64 + i * 16 + l16) * 64 +
                                       ((s * 4 + quad) ^ sw) * 8);
            #pragma unroll
            for (int j = 0; j < 4; j++)
                bfr[j] = *(const bfx8*)(Bs + (wc * 64 + j * 16 + l16) * 64 +
                                        ((s * 4 + quad) ^ sw) * 8);
            #pragma unroll
            for (int i = 0; i < 4; i++)
                #pragma unroll
                for (int j = 0; j < 4; j++)
                    acc[i][j] = MFMA_BF16(af[i], bfr[j], acc[i][j], 0, 0, 0);
        }
        asm volatile("s_waitcnt vmcnt(0)" ::: "memory");   // stage(t+1) landed
        __builtin_amdgcn_s_barrier();                      // buf reuse fence
    }

    if (VSPLIT && n0 >= NQK) {
        // ---- V tile: acc -> LDS (swizzled [d][s]) -> coalesced key-permuted store
        #pragma unroll
        for (int i = 0; i < 4; i++)
            #pragma unroll
            for (int j = 0; j < 4; j++) {
                int d = wc * 64 + j * 16 + l16;
                int s0 = wr * 64 + i * 16 + quad * 4;
                bfx4 pv;
                #pragma unroll
                for (int r = 0; r < 4; r++) pv[r] = (bf16)acc[i][j][r];
                *(bfx4*)((char*)smem + ldsb(d, s0)) = pv;
            }
        __syncthreads();
        int b = m0 >> 11, st = m0 & (Sq - 1), d0 = n0 - NQK;
        int g = (lane >> 3) & 1, t8 = lane & 7;
        int ss = g * 64 + (t8 >> 2) * 32 + (t8 & 3) * 4;
        #pragma unroll
        for (int rep = 0; rep < 8; rep++) {
            int d = wave * 4 + (lane >> 4) + rep * 16;
            bfx4 lo = *(const bfx4*)((char*)smem + ldsb(d, ss));
            bfx4 hi = *(const bfx4*)((char*)smem + ldsb(d, ss + 16));
            bfx8 o8;
            #pragma unroll
            for (int r = 0; r < 4; r++) { o8[r] = lo[r]; o8[4 + r] = hi[r]; }
            *(bfx8*)(Vout + ((size_t)b * Dq + d0 + d) * Sq + st + g * 64 + t8 * 8) = o8;
        }
        return;
    }

    #pragma unroll
    for (int i = 0; i < 4; i++)
        #pragma unroll
        for (int j = 0; j < 4; j++) {
            int col = n0 + wc * 64 + j * 16 + l16;
            int cstride = VSPLIT ? NQK : N;
            float scale = (QSCALE && col < Dq) ? QSC : 1.0f;
            #pragma unroll
            for (int r = 0; r < 4; r++) {
                int row = m0 + wr * 64 + i * 16 + quad * 4 + r;
                if (OUT_F32)
                    ((float*)Cout)[(size_t)row * cstride + col] = acc[i][j][r];
                else
                    ((bf16*)Cout)[(size_t)row * cstride + col] = (bf16)(acc[i][j][r] * scale);
            }
        }
}

// ---------------- Flash attention: counted-vmcnt pipeline, 40KB LDS (4 blocks/CU) --
// 1024 blocks; 4 waves; wave owns 32 q rows.  bid%8 == head%8 (XCD K/V L2 reuse).
// In-register P via key-permuted Vt (R3-verified; bank conflicts 0).  T4 (R8-verified,
// -8us): raw s_barrier + counted s_waitcnt vmcnt(2); only K(i+1) stays in flight
// across each boundary; the loop never drains until the tail.
//   Ledger (2 loads per issue group, in-order vmcnt retirement): prologue issues
//   K0,V0,K1.  Iter i waits vmcnt(2) -> everything except K(i+1) retired, i.e.
//   K(i),V(i) landed; barrier; THEN issue V(i+1)->Vbuf[(i+1)&1] (held V(i-1), done
//   pre-barrier) and K(i+2)->Kbuf[(i+2)%3] (held K(i-1), done pre-barrier).
//   K triple-buffered, V double-buffered: 5 x 8KB = 40KB -> 4 blocks/CU kept.
__global__ __launch_bounds__(256, 4) void attn_kernel(const bf16* __restrict__ qkv,
                                                      const bf16* __restrict__ Vt,
                                                      bf16* __restrict__ out) {
    __shared__ bf16 Ks[3][64 * 64];
    __shared__ bf16 Vs[2][64 * 64];

    int bid = blockIdx.x;
    int qc = (bid >> 3) & 15;                     // q chunk of 128
    int head = ((bid >> 7) << 3) | (bid & 7);     // 0..63; head%8 == bid%8
    int h = head & 15, b = head >> 4;
    int tid = threadIdx.x;
    int lane = tid & 63, wave = tid >> 6;
    int quad = lane >> 4, l16 = lane & 15;
    int sw = l16 & 7;

    size_t base = (size_t)b * Sq * NQK;
    const bf16* Kbase = qkv + base + Dq + h * HDq;
    const bf16* Vbase = Vt + ((size_t)b * Dq + h * HDq) * Sq;
    int q0 = qc * 128 + wave * 32;

    bfx8 qf[2][2];
    #pragma unroll
    for (int qt = 0; qt < 2; qt++)
        #pragma unroll
        for (int s = 0; s < 2; s++)
            qf[qt][s] = *(const bfx8*)(qkv + base + (size_t)(q0 + qt * 16 + l16) * NQK +
                                       h * HDq + s * 32 + quad * 8);

    bfx8 ones;
    #pragma unroll
    for (int j = 0; j < 8; j++) ones[j] = (bf16)1.0f;

    f32x4 oacc[2][4] = {};
    f32x4 lacc[2] = {};

    int c0 = tid, c1 = tid + 256;
    int r0 = c0 >> 3, ch0 = (c0 & 7) ^ (r0 & 7);
    int r1 = c1 >> 3, ch1 = (c1 & 7) ^ (r1 & 7);

    // K buffer rotation: kC = K(i), kN = K(i+1), kF = target for K(i+2)
    bf16 *kC = Ks[0], *kN = Ks[1], *kF = Ks[2];
    bf16 *vC = Vs[0], *vN = Vs[1];

    // prologue: K0, V0, K1   (6 loads/thread outstanding)
    gload_lds16(Kbase + (size_t)r0 * NQK + ch0 * 8, kC + c0 * 8);
    gload_lds16(Kbase + (size_t)r1 * NQK + ch1 * 8, kC + c1 * 8);
    gload_lds16(Vbase + (size_t)r0 * Sq + ch0 * 8, vC + c0 * 8);
    gload_lds16(Vbase + (size_t)r1 * Sq + ch1 * 8, vC + c1 * 8);
    gload_lds16(Kbase + (size_t)(64 + r0) * NQK + ch0 * 8, kN + c0 * 8);
    gload_lds16(Kbase + (size_t)(64 + r1) * NQK + ch1 * 8, kN + c1 * 8);

    #pragma unroll 1
    for (int i = 0; i < 32; i++) {
        if (i < 31) asm volatile("s_waitcnt vmcnt(2)" ::: "memory");
        else        asm volatile("s_waitcnt vmcnt(0)" ::: "memory");
        __builtin_amdgcn_s_barrier();
        if (i + 1 < 32) {           // V(i+1) -> buffer of V(i-1) (safe post-barrier)
            int k0 = (i + 1) * 64;
            gload_lds16(Vbase + (size_t)r0 * Sq + k0 + ch0 * 8, vN + c0 * 8);
            gload_lds16(Vbase + (size_t)r1 * Sq + k0 + ch1 * 8, vN + c1 * 8);
        }
        if (i + 2 < 32) {           // K(i+2) -> buffer of K(i-1) (safe post-barrier)
            int k0 = (i + 2) * 64;
            gload_lds16(Kbase + (size_t)(k0 + r0) * NQK + ch0 * 8, kF + c0 * 8);
            gload_lds16(Kbase + (size_t)(k0 + r1) * NQK + ch1 * 8, kF + c1 * 8);
        }
        const bf16* K_ = kC;
        const bf16* V_ = vC;

        #pragma unroll
        for (int hf = 0; hf < 2; hf++) {
            bfx8 kf[2][2];
            #pragma unroll
            for (int tp = 0; tp < 2; tp++) {
                int krow = ((2 * hf + tp) * 16 + l16) * 64;
                kf[tp][0] = *(const bfx8*)(K_ + krow + (quad ^ sw) * 8);
                kf[tp][1] = *(const bfx8*)(K_ + krow + ((4 + quad) ^ sw) * 8);
            }

            bfx8 pf[2];
            #pragma unroll
            for (int qt = 0; qt < 2; qt++) {
                f32x4 s0 = {}, s1 = {};
                s0 = MFMA_BF16(kf[0][0], qf[qt][0], s0, 0, 0, 0);
                s0 = MFMA_BF16(kf[0][1], qf[qt][1], s0, 0, 0, 0);
                s1 = MFMA_BF16(kf[1][0], qf[qt][0], s1, 0, 0, 0);
                s1 = MFMA_BF16(kf[1][1], qf[qt][1], s1, 0, 0, 0);
                bfx8 p;
                #pragma unroll
                for (int r = 0; r < 4; r++) {
                    p[r]     = (bf16)fast_exp2(s0[r]);   // key 4*quad + r
                    p[4 + r] = (bf16)fast_exp2(s1[r]);   // key 16 + 4*quad + r
                }
                pf[qt] = p;
                lacc[qt] = MFMA_BF16(pf[qt], ones, lacc[qt], 0, 0, 0);
            }

            #pragma unroll
            for (int nt = 0; nt < 4; nt++) {
                bfx8 vf = *(const bfx8*)(V_ + (nt * 16 + l16) * 64 +
                                         ((hf * 4 + quad) ^ sw) * 8);
                oacc[0][nt] = MFMA_BF16(pf[0], vf, oacc[0][nt], 0, 0, 0);
                oacc[1][nt] = MFMA_BF16(pf[1], vf, oacc[1][nt], 0, 0, 0);
            }
        }

        // rotate buffers
        bf16* kt = kC; kC = kN; kN = kF; kF = kt;
        bf16* vt = vC; vC = vN; vN = vt;
    }

    #pragma unroll
    for (int qt = 0; qt < 2; qt++)
        #pragma unroll
        for (int r = 0; r < 4; r++) {
            int row = q0 + qt * 16 + quad * 4 + r;
            float inv = 1.0f / lacc[qt][r];
            #pragma unroll
            for (int nt = 0; nt < 4; nt++)
                out[((size_t)b * Sq + row) * Dq + h * HDq + nt * 16 + l16] =
                    (bf16)(oacc[qt][nt][r] * inv);
        }
}

extern "C" void kernel_launch(void* const* d_in, const int* in_sizes, int n_in,
                              void* d_out, int out_size, void* d_ws, size_t ws_size,
                              hipStream_t stream) {
    const float* x     = (const float*)d_in[0];
    const float* w_qkv = (const float*)d_in[1];
    const float* w_out = (const float*)d_in[2];
    float* out = (float*)d_out;

    char* ws = (char*)d_ws;
    bf16* x_bf   = (bf16*)ws;                                   // 16 MB (dead after gemm1)
    bf16* wqkvT  = (bf16*)(ws + 16777216);                      //  6 MB
    bf16* woutT  = (bf16*)(ws + 16777216 + 6291456);            //  2 MB
    bf16* qkv2   = (bf16*)(ws + 25165824);                      // 32 MB: Q,K stride 2048
    bf16* Vt     = (bf16*)(ws + 25165824 + 33554432);           // 16 MB: V^T key-permuted
    bf16* attn   = x_bf;   // x_bf dead after gemm1; reuse for attention output

    // 1. prep: cast x + transpose both weights (single launch)
    prep<<<8192 + 3072 + 1024, 256, 0, stream>>>(x, w_qkv, w_out, x_bf, wqkvT, woutT);

    // 2. qkv = x @ w_qkv: Q,K -> qkv2 (Q pre-scaled); V -> Vt via coalesced LDS epilogue
    gemm_bt<false, true, true><<<dim3(D3 / 128, Mq / 128), 256, 0, stream>>>(
        x_bf, wqkvT, qkv2, Vt, Mq, D3, Dq);

    // 3. attention (1024 blocks, XCD-affine, 40KB LDS, counted-vmcnt pipeline)
    attn_kernel<<<1024, 256, 0, stream>>>(qkv2, Vt, attn);

    // 4. out = attn @ w_out  [8192 x 1024], fp32 out
    gemm_bt<true, false, false><<<dim3(Dq / 128, Mq / 128), 256, 0, stream>>>(
        attn, woutT, out, nullptr, Mq, Dq, Dq);
}